// Round 4
// baseline (201.582 us; speedup 1.0000x reference)
//
#include <hip/hip_runtime.h>

// Separable 2D bicubic antialiased resize, scale=0.5 on H and W:
// x: (8,3,1024,1024) fp32 -> out: (8,3,512,512) fp32.
//
// out[b,c,oh,ow] = sum_k0 w0[k0,oh] * sum_k1 w1[k1,ow] * x[b,c, fov0[k0,oh], fov1[k1,ow]]
//
// K=8 taps/dim for this config; interior outputs (q in [2,509]) read 8
// CONSECUTIVE input rows/cols (2q-3 .. 2q+4). Single dispatch:
//   blockIdx.y < 32 : interior, coalesced float4 window loads, per-thread
//                     verification against the tables (exact gather fallback)
//   blockIdx.y == 32: mirrored border outputs, table-driven gather
//
// Verified on paper: weights 0.5*cubic({1.75,1.25,0.75,0.25}) sum to 1.0,
// col_base = 4T-4 (float4-aligned), 14-row window per 4 output rows.

#define IH 1024
#define IW 1024
#define OH 512
#define OW 512
#define NBC 24           // 8 batches * 3 channels
#define EDGE_PER_BC 4080 // 4 border rows * 512 + 4 border cols * 508

__global__ __launch_bounds__(256) void resize_k8(
    const float* __restrict__ x,
    const float* __restrict__ w0, const int* __restrict__ fov0,
    const float* __restrict__ w1, const int* __restrict__ fov1,
    float* __restrict__ out)
{
    const int bc = blockIdx.z;
    const float* __restrict__ xp = x + (size_t)bc * (IH * IW);
    float*       __restrict__ op = out + (size_t)bc * (OH * OW);

    // ================= edge blocks: mirrored borders, table-driven =========
    if (blockIdx.y == 32) {
        const int et = blockIdx.x * 256 + threadIdx.y * 64 + threadIdx.x; // 0..1023
#pragma unroll
        for (int i = 0; i < 4; ++i) {
            const int e = et + i * 1024;
            if (e < EDGE_PER_BC) {
                int oh, q;
                if (e < 2048) {                 // border rows {0,1,510,511}, all cols
                    const int rr = e >> 9;
                    oh = (rr < 2) ? rr : (OH - 4 + rr);
                    q  = e & 511;
                } else {                        // border cols {0,1,510,511}, rows 2..509
                    const int e2 = e - 2048;
                    const int cc = e2 / 508;
                    q  = (cc < 2) ? cc : (OW - 4 + cc);
                    oh = 2 + e2 % 508;
                }
                float acc = 0.f;
                for (int k0 = 0; k0 < 8; ++k0) {
                    const float wv = w0[k0 * OH + oh];
                    const float* rp = xp + (size_t)fov0[k0 * OH + oh] * IW;
                    float h = 0.f;
                    for (int k1 = 0; k1 < 8; ++k1)
                        h = fmaf(w1[k1 * OW + q], rp[fov1[k1 * OW + q]], h);
                    acc = fmaf(wv, h, acc);
                }
                op[(size_t)oh * OW + q] = acc;
            }
        }
        return;
    }

    // ================= interior blocks ====================================
    const int T = blockIdx.x * 64 + threadIdx.x;   // global output-col pair id
    if (T == 0 || T == 255) return;                // border col pairs -> edge blocks
    const int q0  = 2 * T;
    const int q1  = q0 + 1;
    const int oh0 = blockIdx.y * 16 + threadIdx.y * 4;  // 4 consecutive output rows

    // ---- load taps (tables are small & cache-hot)
    float wx0[8], wx1[8], wy[4][8];
    int   cx0[8], cx1[8];
#pragma unroll
    for (int k = 0; k < 8; ++k) {
        wx0[k] = w1[k * OW + q0];  cx0[k] = fov1[k * OW + q0];
        wx1[k] = w1[k * OW + q1];  cx1[k] = fov1[k * OW + q1];
    }
    const int col_base = cx0[0] - 1;           // float4-aligned window base col
    int row_base = 0;
    bool ok = (col_base >= 0) & ((col_base & 3) == 0) & (col_base + 12 <= IW);
#pragma unroll
    for (int k = 0; k < 8; ++k)
        ok = ok & (cx0[k] == col_base + 1 + k) & (cx1[k] == col_base + 3 + k);

    {
        const int rb = fov0[oh0];              // k=0 tap of first output row
        row_base = rb;
        ok = ok & (rb >= 0) & (rb + 14 <= IH);
#pragma unroll
        for (int r = 0; r < 4; ++r)
#pragma unroll
            for (int k = 0; k < 8; ++k) {
                wy[r][k] = w0[k * OH + (oh0 + r)];
                ok = ok & (fov0[k * OH + (oh0 + r)] == rb + 2 * r + k);
            }
    }

    if (ok) {
        // ---- fast path: 14 input rows x 12 cols, 3 float4 loads per row
        float acc[4][2];
#pragma unroll
        for (int r = 0; r < 4; ++r) { acc[r][0] = 0.f; acc[r][1] = 0.f; }

#pragma unroll
        for (int i = 0; i < 14; ++i) {
            const float* rp = xp + (size_t)(row_base + i) * IW + col_base;
            const float4 a = *reinterpret_cast<const float4*>(rp);
            const float4 b = *reinterpret_cast<const float4*>(rp + 4);
            const float4 c = *reinterpret_cast<const float4*>(rp + 8);
            const float v[12] = { a.x, a.y, a.z, a.w,
                                  b.x, b.y, b.z, b.w,
                                  c.x, c.y, c.z, c.w };
            float h0 = 0.f, h1 = 0.f;
#pragma unroll
            for (int k = 0; k < 8; ++k) {
                h0 = fmaf(wx0[k], v[1 + k], h0);
                h1 = fmaf(wx1[k], v[3 + k], h1);
            }
            // input row i feeds output row r when 0 <= i-2r < 8 (compile-time)
#pragma unroll
            for (int r = 0; r < 4; ++r) {
                if (i - 2 * r >= 0 && i - 2 * r < 8) {
                    acc[r][0] = fmaf(wy[r][i - 2 * r], h0, acc[r][0]);
                    acc[r][1] = fmaf(wy[r][i - 2 * r], h1, acc[r][1]);
                }
            }
        }

#pragma unroll
        for (int r = 0; r < 4; ++r) {
            const int oh = oh0 + r;
            if (oh >= 2 && oh < OH - 2) {
                const float2 v2 = make_float2(acc[r][0], acc[r][1]);
                *reinterpret_cast<float2*>(op + (size_t)oh * OW + q0) = v2;
            }
        }
    } else {
        // ---- exact fallback: re-read tables, gather (only border-straddling waves)
#pragma unroll
        for (int r = 0; r < 4; ++r) {
            const int oh = oh0 + r;
            if (oh < 2 || oh >= OH - 2) continue;  // border rows -> edge blocks
            float a0 = 0.f, a1 = 0.f;
            for (int k0 = 0; k0 < 8; ++k0) {
                const float wv = w0[k0 * OH + oh];
                const float* rp = xp + (size_t)fov0[k0 * OH + oh] * IW;
                float h0 = 0.f, h1 = 0.f;
                for (int k1 = 0; k1 < 8; ++k1) {
                    h0 = fmaf(w1[k1 * OW + q0], rp[fov1[k1 * OW + q0]], h0);
                    h1 = fmaf(w1[k1 * OW + q1], rp[fov1[k1 * OW + q1]], h1);
                }
                a0 = fmaf(wv, h0, a0);
                a1 = fmaf(wv, h1, a1);
            }
            op[(size_t)oh * OW + q0] = a0;
            op[(size_t)oh * OW + q1] = a1;
        }
    }
}

// ---------------- generic fallback for unexpected K ----------------
__global__ __launch_bounds__(256) void resize_gen(
    const float* __restrict__ x,
    const float* __restrict__ w0, const int* __restrict__ fov0,
    const float* __restrict__ w1, const int* __restrict__ fov1,
    float* __restrict__ out, int K0, int K1)
{
    const int ow = blockIdx.x * 64 + threadIdx.x;
    const int oh = blockIdx.y * 4 + threadIdx.y;
    const int bc = blockIdx.z;

    const float* __restrict__ xp = x + (size_t)bc * (IH * IW);

    float acc = 0.f;
    for (int k0 = 0; k0 < K0; ++k0) {
        const float wyk = w0[k0 * OH + oh];
        const float* __restrict__ rp = xp + (size_t)fov0[k0 * OH + oh] * IW;
        float h = 0.f;
        for (int k1 = 0; k1 < K1; ++k1)
            h = fmaf(w1[k1 * OW + ow], rp[fov1[k1 * OW + ow]], h);
        acc = fmaf(wyk, h, acc);
    }
    out[(size_t)bc * (OH * OW) + (size_t)oh * OW + ow] = acc;
}

extern "C" void kernel_launch(void* const* d_in, const int* in_sizes, int n_in,
                              void* d_out, int out_size, void* d_ws, size_t ws_size,
                              hipStream_t stream)
{
    const float* x    = (const float*)d_in[0];
    const float* w0   = (const float*)d_in[1];
    const int*   fov0 = (const int*)d_in[2];
    const float* w1   = (const float*)d_in[3];
    const int*   fov1 = (const int*)d_in[4];
    float* out = (float*)d_out;

    const int K0 = in_sizes[1] / OH;
    const int K1 = in_sizes[3] / OW;

    if (K0 == 8 && K1 == 8) {
        dim3 block(64, 4, 1);
        dim3 grid(OW / 128, 33, NBC);   // y: 0..31 interior, 32 = border work
        resize_k8<<<grid, block, 0, stream>>>(x, w0, fov0, w1, fov1, out);
    } else {
        dim3 block(64, 4, 1);
        dim3 grid(OW / 64, OH / 4, NBC);
        resize_gen<<<grid, block, 0, stream>>>(x, w0, fov0, w1, fov1, out, K0, K1);
    }
}

// Round 5
// 178.092 us; speedup vs baseline: 1.1319x; 1.1319x over previous
//
#include <hip/hip_runtime.h>

// Separable 2D bicubic antialiased resize, scale=0.5 on H and W:
// x: (8,3,1024,1024) fp32 -> out: (8,3,512,512) fp32.
//
// out[b,c,oh,ow] = sum_k0 w0[k0,oh] * sum_k1 w1[k1,ow] * x[b,c, fov0[k0,oh], fov1[k1,ow]]
//
// K=8 taps/dim; by construction of the tables, fov[k][q] == mirror(2q-3+k)
// for ALL q (mirror = reflect at 0 and 1024). Round-4 HW run validated the
// interior structure (passed). This version:
//   - stages a mirror-indexed 136x38 input tile into LDS per block
//     (6 independent float4 loads/thread -> high MLP; Round-4 kernel was
//     latency-bound at ILP~1, 440 cyc/load, 87 us)
//   - computes a 64x16 output tile from LDS (stride-2 float2 reads = free
//     2-way bank aliasing; h-sums reused across 4 output rows)
//   - single uniform path for interior AND borders (mirroring baked into
//     the staged tile; weights always read from the tables)
//   - per-thread verification vs the fov tables with exact global fallback

#define IH 1024
#define IW 1024
#define OH 512
#define OW 512
#define NBC 24        // 8 batches * 3 channels

#define TILE_OC 64    // output cols per block
#define TILE_OR 16    // output rows per block
#define IC 136        // staged input cols  (covers 2*c0-4 .. 2*c0+131)
#define IR 38         // staged input rows  (covers 2*r0-3 .. 2*r0+34)
#define NF4 (IC / 4)  // 34 float4 per staged row
#define NSTG (IR * NF4)  // 1292 float4 loads per block

__device__ __forceinline__ int mir(int i) {
    i = (i < 0) ? (-1 - i) : i;
    return (i >= IH) ? (2 * IH - 1 - i) : i;   // IH == IW
}

__global__ __launch_bounds__(256) void resize_tile(
    const float* __restrict__ x,
    const float* __restrict__ w0, const int* __restrict__ fov0,
    const float* __restrict__ w1, const int* __restrict__ fov1,
    float* __restrict__ out)
{
    __shared__ float lds[IR][IC];

    const int tid = threadIdx.x;
    const int c0  = blockIdx.x * TILE_OC;
    const int r0  = blockIdx.y * TILE_OR;
    const int bc  = blockIdx.z;

    const float* __restrict__ xp = x + (size_t)bc * (IH * IW);
    float*       __restrict__ op = out + (size_t)bc * (OH * OW);

    const int colBase = 2 * c0 - 4;   // float4-aligned (c0 multiple of 64)
    const int rowBase = 2 * r0 - 3;

    // ---- stage: issue ALL global loads first (6 independent float4/thread),
    //      then all LDS writes. Mirror-index out-of-range rows/cols.
    float4 vals[6];
#pragma unroll
    for (int i = 0; i < 6; ++i) {
        const int idx = tid + i * 256;
        if (idx < NSTG) {
            const int r  = idx / NF4;
            const int c4 = idx % NF4;
            const int gr = mir(rowBase + r);
            const int gc = colBase + 4 * c4;
            const float* rowp = xp + (size_t)gr * IW;
            if (gc >= 0 && gc <= IW - 4) {
                vals[i] = *reinterpret_cast<const float4*>(rowp + gc);
            } else {                       // image edge: per-element mirror
                vals[i].x = rowp[mir(gc)];
                vals[i].y = rowp[mir(gc + 1)];
                vals[i].z = rowp[mir(gc + 2)];
                vals[i].w = rowp[mir(gc + 3)];
            }
        }
    }
#pragma unroll
    for (int i = 0; i < 6; ++i) {
        const int idx = tid + i * 256;
        if (idx < NSTG) {
            const int r  = idx / NF4;
            const int c4 = idx % NF4;
            *reinterpret_cast<float4*>(&lds[r][4 * c4]) = vals[i];
        }
    }
    __syncthreads();

    // ---- compute: wave-uniform rows (ty), per-lane col (tx)
    const int tx = tid & 63;
    const int ty = tid >> 6;            // 0..3 -> 4 output rows each
    const int q  = c0 + tx;
    const int ro_base = ty * 4;

    float wx[8];
    bool ok = true;
#pragma unroll
    for (int k = 0; k < 8; ++k) {
        wx[k] = w1[k * OW + q];
        ok &= (fov1[k * OW + q] == mir(2 * q - 3 + k));
    }
    float wy[4][8];
#pragma unroll
    for (int rr = 0; rr < 4; ++rr) {
        const int oh = r0 + ro_base + rr;
#pragma unroll
        for (int k = 0; k < 8; ++k) {
            wy[rr][k] = w0[k * OH + oh];
            ok &= (fov0[k * OH + oh] == mir(2 * oh - 3 + k));
        }
    }

    if (ok) {
        float acc[4] = {0.f, 0.f, 0.f, 0.f};
        const int lc = 2 * tx;          // local col of tap window start - 1
#pragma unroll
        for (int i = 0; i < 14; ++i) {
            const int lr = 2 * ro_base + i;
            const float2 p0 = *reinterpret_cast<const float2*>(&lds[lr][lc]);
            const float2 p1 = *reinterpret_cast<const float2*>(&lds[lr][lc + 2]);
            const float2 p2 = *reinterpret_cast<const float2*>(&lds[lr][lc + 4]);
            const float2 p3 = *reinterpret_cast<const float2*>(&lds[lr][lc + 6]);
            const float2 p4 = *reinterpret_cast<const float2*>(&lds[lr][lc + 8]);
            float h;
            h = wx[0] * p0.y;
            h = fmaf(wx[1], p1.x, h);
            h = fmaf(wx[2], p1.y, h);
            h = fmaf(wx[3], p2.x, h);
            h = fmaf(wx[4], p2.y, h);
            h = fmaf(wx[5], p3.x, h);
            h = fmaf(wx[6], p3.y, h);
            h = fmaf(wx[7], p4.x, h);
            // input row i feeds output row rr when 0 <= i-2rr < 8 (static)
#pragma unroll
            for (int rr = 0; rr < 4; ++rr) {
                const int k0 = i - 2 * rr;
                if (k0 >= 0 && k0 < 8)
                    acc[rr] = fmaf(wy[rr][k0], h, acc[rr]);
            }
        }
#pragma unroll
        for (int rr = 0; rr < 4; ++rr)
            op[(size_t)(r0 + ro_base + rr) * OW + q] = acc[rr];
    } else {
        // ---- exact fallback: table-driven gather from global (never in practice)
#pragma unroll
        for (int rr = 0; rr < 4; ++rr) {
            const int oh = r0 + ro_base + rr;
            float a = 0.f;
            for (int k0 = 0; k0 < 8; ++k0) {
                const float* rp = xp + (size_t)fov0[k0 * OH + oh] * IW;
                float h = 0.f;
                for (int k1 = 0; k1 < 8; ++k1)
                    h = fmaf(w1[k1 * OW + q], rp[fov1[k1 * OW + q]], h);
                a = fmaf(w0[k0 * OH + oh], h, a);
            }
            op[(size_t)oh * OW + q] = a;
        }
    }
}

// ---------------- generic fallback for unexpected K ----------------
__global__ __launch_bounds__(256) void resize_gen(
    const float* __restrict__ x,
    const float* __restrict__ w0, const int* __restrict__ fov0,
    const float* __restrict__ w1, const int* __restrict__ fov1,
    float* __restrict__ out, int K0, int K1)
{
    const int ow = blockIdx.x * 64 + threadIdx.x;
    const int oh = blockIdx.y * 4 + threadIdx.y;
    const int bc = blockIdx.z;

    const float* __restrict__ xp = x + (size_t)bc * (IH * IW);

    float acc = 0.f;
    for (int k0 = 0; k0 < K0; ++k0) {
        const float wyk = w0[k0 * OH + oh];
        const float* __restrict__ rp = xp + (size_t)fov0[k0 * OH + oh] * IW;
        float h = 0.f;
        for (int k1 = 0; k1 < K1; ++k1)
            h = fmaf(w1[k1 * OW + ow], rp[fov1[k1 * OW + ow]], h);
        acc = fmaf(wyk, h, acc);
    }
    out[(size_t)bc * (OH * OW) + (size_t)oh * OW + ow] = acc;
}

extern "C" void kernel_launch(void* const* d_in, const int* in_sizes, int n_in,
                              void* d_out, int out_size, void* d_ws, size_t ws_size,
                              hipStream_t stream)
{
    const float* x    = (const float*)d_in[0];
    const float* w0   = (const float*)d_in[1];
    const int*   fov0 = (const int*)d_in[2];
    const float* w1   = (const float*)d_in[3];
    const int*   fov1 = (const int*)d_in[4];
    float* out = (float*)d_out;

    const int K0 = in_sizes[1] / OH;
    const int K1 = in_sizes[3] / OW;

    if (K0 == 8 && K1 == 8) {
        dim3 block(256, 1, 1);
        dim3 grid(OW / TILE_OC, OH / TILE_OR, NBC);   // (8, 32, 24)
        resize_tile<<<grid, block, 0, stream>>>(x, w0, fov0, w1, fov1, out);
    } else {
        dim3 block(64, 4, 1);
        dim3 grid(OW / 64, OH / 4, NBC);
        resize_gen<<<grid, block, 0, stream>>>(x, w0, fov0, w1, fov1, out, K0, K1);
    }
}

// Round 6
// 169.845 us; speedup vs baseline: 1.1869x; 1.0486x over previous
//
#include <hip/hip_runtime.h>

// Separable 2D bicubic antialiased resize, scale=0.5 on H and W:
// x: (8,3,1024,1024) fp32 -> out: (8,3,512,512) fp32.
//
// out[b,c,oh,ow] = sum_k0 w0[k0,oh] * sum_k1 w1[k1,ow] * x[.., fov0[k0,oh], fov1[k1,ow]]
//
// Facts (HW-validated rounds 4/5): K=8 taps/dim; fov[k][q] == mir(2q-3+k) for
// ALL q (mirror reflect at 0/1024); for scale=0.5 the 8 tap weights are the
// SAME for every output row/col (dyadic rationals, sum exactly 1.0).
//
// Round-5 was latency/VALU-bound (64us, VALU 38%, LDS conflicts 14% of cyc,
// occupancy 28%): per-thread verification (~200 VALU ops) out-weighed the
// 144 real FMAs, and stride-2 float2 LDS reads re-read the tile 4.7x with
// 4-way bank aliasing. This version:
//   phase A: each thread computes ~5 horizontal 8-tap sums (h) straight from
//            global (3 independent float4 loads per h-pair, 15 loads in
//            flight), writes h into a 38x64 LDS buffer (9.7 KB only).
//   phase B: vertical 8-tap over LDS h rows (contiguous 256B wave reads,
//            conflict-free), 4 output rows/thread, h reused across rows.
//   verification: per-BLOCK (640 table entries, ~3 checks/thread) + wave
//            ballot vote; on failure the whole block takes an exact
//            table-driven gather path. Weight uniformity is part of the check.

#define IH 1024
#define IW 1024
#define OH 512
#define OW 512

#define TILE_OC 64
#define TILE_OR 16
#define HR 38               // h rows staged = 2*TILE_OR + 6
#define NPAIR (TILE_OC / 2) // 32 h-col pairs per row
#define NTASK (HR * NPAIR)  // 1216
#define NITER 5             // ceil(NTASK / 256)

__device__ __forceinline__ int mir(int i) {
    i = (i < 0) ? (-1 - i) : i;
    return (i >= IH) ? (2 * IH - 1 - i) : i;   // IH == IW
}

__global__ __launch_bounds__(256) void resize_fused(
    const float* __restrict__ x,
    const float* __restrict__ w0, const int* __restrict__ fov0,
    const float* __restrict__ w1, const int* __restrict__ fov1,
    float* __restrict__ out)
{
    __shared__ float hbuf[HR][TILE_OC];   // 9728 B
    __shared__ int   svote[4];

    const int tid  = threadIdx.x;
    const int lane = tid & 63;
    const int wid  = tid >> 6;
    const int c0   = blockIdx.x * TILE_OC;
    const int r0   = blockIdx.y * TILE_OR;
    const int bc   = blockIdx.z;

    const float* __restrict__ xp = x + (size_t)bc * (IH * IW);
    float*       __restrict__ op = out + (size_t)bc * (OH * OW);

    const int rowBase = 2 * r0 - 3;

    // block-uniform tap weights (verified against the tables below)
    float wx[8], wy[8];
#pragma unroll
    for (int k = 0; k < 8; ++k) {
        wx[k] = w1[k * OW + c0];
        wy[k] = w0[k * OH + r0];
    }

    // ---- phase A: issue ALL global loads first (up to 15 independent float4)
    float4 A[NITER], B[NITER], C[NITER];
#pragma unroll
    for (int it = 0; it < NITER; ++it) {
        const int idx = tid + it * 256;
        if (idx < NTASK) {
            const int r  = idx >> 5;        // h row 0..37
            const int p  = idx & 31;        // col-pair
            const int gr = mir(rowBase + r);
            const int gc = 2 * c0 + 4 * p - 4;
            const float* rp = xp + (size_t)gr * IW;
            if (gc >= 0 && gc + 12 <= IW) {
                A[it] = *reinterpret_cast<const float4*>(rp + gc);
                B[it] = *reinterpret_cast<const float4*>(rp + gc + 4);
                C[it] = *reinterpret_cast<const float4*>(rp + gc + 8);
            } else {  // image edge: per-element mirrored loads
                A[it].x = rp[mir(gc +  0)]; A[it].y = rp[mir(gc +  1)];
                A[it].z = rp[mir(gc +  2)]; A[it].w = rp[mir(gc +  3)];
                B[it].x = rp[mir(gc +  4)]; B[it].y = rp[mir(gc +  5)];
                B[it].z = rp[mir(gc +  6)]; B[it].w = rp[mir(gc +  7)];
                C[it].x = rp[mir(gc +  8)]; C[it].y = rp[mir(gc +  9)];
                C[it].z = rp[mir(gc + 10)]; C[it].w = rp[mir(gc + 11)];
            }
        }
    }

    // ---- per-block table verification (overlaps with load latency)
    bool okt = true;
#pragma unroll
    for (int s = 0; s < 2; ++s) {          // 512 fov1/w1 entries, 2 per thread
        const int e = tid + s * 256;
        const int k = e >> 6;
        const int q = c0 + (e & 63);
        okt = okt & (fov1[k * OW + q] == mir(2 * q - 3 + k));
        okt = okt & (w1[k * OW + q] == wx[k]);
    }
    if (tid < 128) {                       // 128 fov0/w0 entries
        const int k  = tid >> 4;
        const int oh = r0 + (tid & 15);
        okt = okt & (fov0[k * OH + oh] == mir(2 * oh - 3 + k));
        okt = okt & (w0[k * OH + oh] == wy[k]);
    }
    const unsigned long long bal = __ballot(okt);
    if (lane == 0) svote[wid] = (~bal == 0ull) ? 1 : 0;

    // ---- phase A compute: h pairs -> LDS
#pragma unroll
    for (int it = 0; it < NITER; ++it) {
        const int idx = tid + it * 256;
        if (idx < NTASK) {
            const int r = idx >> 5;
            const int p = idx & 31;
            const float v[12] = { A[it].x, A[it].y, A[it].z, A[it].w,
                                  B[it].x, B[it].y, B[it].z, B[it].w,
                                  C[it].x, C[it].y, C[it].z, C[it].w };
            float h0 = wx[0] * v[1];
            float h1 = wx[0] * v[3];
#pragma unroll
            for (int k = 1; k < 8; ++k) {
                h0 = fmaf(wx[k], v[1 + k], h0);
                h1 = fmaf(wx[k], v[3 + k], h1);
            }
            *reinterpret_cast<float2*>(&hbuf[r][2 * p]) = make_float2(h0, h1);
        }
    }
    __syncthreads();

    const bool fast = (svote[0] & svote[1] & svote[2] & svote[3]) != 0;
    const int  q    = c0 + lane;
    const int  oh0  = r0 + wid * 4;

    if (fast) {
        // ---- phase B: vertical 8-tap from LDS, 4 output rows/thread
        float acc[4] = {0.f, 0.f, 0.f, 0.f};
#pragma unroll
        for (int i = 0; i < 14; ++i) {
            const float h = hbuf[8 * wid + i][lane];
#pragma unroll
            for (int rr = 0; rr < 4; ++rr) {
                const int k0 = i - 2 * rr;
                if (k0 >= 0 && k0 < 8)
                    acc[rr] = fmaf(wy[k0], h, acc[rr]);
            }
        }
#pragma unroll
        for (int rr = 0; rr < 4; ++rr)
            op[(size_t)(oh0 + rr) * OW + q] = acc[rr];
    } else {
        // ---- exact fallback for the whole block (tables disagreed)
        for (int rr = 0; rr < 4; ++rr) {
            const int oh = oh0 + rr;
            float a = 0.f;
            for (int k0 = 0; k0 < 8; ++k0) {
                const float* rp = xp + (size_t)fov0[k0 * OH + oh] * IW;
                float h = 0.f;
                for (int k1 = 0; k1 < 8; ++k1)
                    h = fmaf(w1[k1 * OW + q], rp[fov1[k1 * OW + q]], h);
                a = fmaf(w0[k0 * OH + oh], h, a);
            }
            op[(size_t)oh * OW + q] = a;
        }
    }
}

// ---------------- generic fallback for unexpected K ----------------
__global__ __launch_bounds__(256) void resize_gen(
    const float* __restrict__ x,
    const float* __restrict__ w0, const int* __restrict__ fov0,
    const float* __restrict__ w1, const int* __restrict__ fov1,
    float* __restrict__ out, int K0, int K1)
{
    const int ow = blockIdx.x * 64 + threadIdx.x;
    const int oh = blockIdx.y * 4 + threadIdx.y;
    const int bc = blockIdx.z;

    const float* __restrict__ xp = x + (size_t)bc * (IH * IW);

    float acc = 0.f;
    for (int k0 = 0; k0 < K0; ++k0) {
        const float wyk = w0[k0 * OH + oh];
        const float* __restrict__ rp = xp + (size_t)fov0[k0 * OH + oh] * IW;
        float h = 0.f;
        for (int k1 = 0; k1 < K1; ++k1)
            h = fmaf(w1[k1 * OW + ow], rp[fov1[k1 * OW + ow]], h);
        acc = fmaf(wyk, h, acc);
    }
    out[(size_t)bc * (OH * OW) + (size_t)oh * OW + ow] = acc;
}

extern "C" void kernel_launch(void* const* d_in, const int* in_sizes, int n_in,
                              void* d_out, int out_size, void* d_ws, size_t ws_size,
                              hipStream_t stream)
{
    const float* x    = (const float*)d_in[0];
    const float* w0   = (const float*)d_in[1];
    const int*   fov0 = (const int*)d_in[2];
    const float* w1   = (const float*)d_in[3];
    const int*   fov1 = (const int*)d_in[4];
    float* out = (float*)d_out;

    const int nbc = in_sizes[0] / (IH * IW);   // 24 for this problem
    const int K0  = in_sizes[1] / OH;
    const int K1  = in_sizes[3] / OW;

    if (K0 == 8 && K1 == 8) {
        dim3 block(256, 1, 1);
        dim3 grid(OW / TILE_OC, OH / TILE_OR, nbc);   // (8, 32, 24)
        resize_fused<<<grid, block, 0, stream>>>(x, w0, fov0, w1, fov1, out);
    } else {
        dim3 block(64, 4, 1);
        dim3 grid(OW / 64, OH / 4, nbc);
        resize_gen<<<grid, block, 0, stream>>>(x, w0, fov0, w1, fov1, out, K0, K1);
    }
}